// Round 3
// baseline (120.332 us; speedup 1.0000x reference)
//
#include <hip/hip_runtime.h>

// Overlapped-chunk HMM forward filter, all-VALU inner loop.
// CHUNK_L=32, WARMUP_W=16 -> 15625 chunks, ~3.8 waves/SIMD, work 1.5x T.
//
// R8 = MEASUREMENT ROUND. R6's y-latency fixes (4-deep pipeline, hoisted
// first-touch, pure dot->mul chain) produced ZERO total delta (95.24->95.58),
// killing the latency theory. The kernel's dispatch is invisible in top-5
// rocprof rows (all are 44-46us poison fills), so its true duration is
// unknown (could be ~40us or ~10us). This round launches the IDENTICAL
// kernel TWICE back-to-back on the same stream: the kernel is idempotent
// (deterministic writes from const inputs), so dur_us_new - dur_us_old =
// warm-kernel duration. Pre-committed reads:
//   dur ~130-135 -> kernel ~40us, keep optimizing (throughput-bound);
//   dur ~103-108 -> kernel ~10us, harness poison floor -> ROOFLINE;
//   dur ~115     -> kernel ~20us, work-reduction levers next.
#define CHUNK_L 32
#define WARMUP_W 16

typedef float v2f __attribute__((ext_vector_type(2)));

template<int K> __device__ __forceinline__ float bcast16(float v) {
    // broadcast lane (row_start + K) across the 16-lane row (row_newbcast)
    return __int_as_float(__builtin_amdgcn_update_dpp(
        0, __float_as_int(v), 0x150 | K, 0xF, 0xF, true));
}
template<int N> __device__ __forceinline__ float rowror16(float v) {
    return __int_as_float(__builtin_amdgcn_update_dpp(
        0, __float_as_int(v), 0x120 | N, 0xF, 0xF, true));
}

__device__ __forceinline__ float rowsum16(float p) {
    p += rowror16<1>(p);
    p += rowror16<2>(p);
    p += rowror16<4>(p);
    p += rowror16<8>(p);
    return p;
}

// (a @ P)_j : 16 DPP broadcasts + 8 v_pk_fma_f32 (2 indep accumulator pairs)
__device__ __forceinline__ float dot16(float a, const v2f* pc2) {
    v2f b0, b1, u01, u23;
    b0.x = bcast16<0>(a);  b0.y = bcast16<1>(a);
    b1.x = bcast16<2>(a);  b1.y = bcast16<3>(a);
    u01 = b0 * pc2[0];
    u23 = b1 * pc2[1];
    b0.x = bcast16<4>(a);  b0.y = bcast16<5>(a);
    b1.x = bcast16<6>(a);  b1.y = bcast16<7>(a);
    u01 = b0 * pc2[2] + u01;
    u23 = b1 * pc2[3] + u23;
    b0.x = bcast16<8>(a);  b0.y = bcast16<9>(a);
    b1.x = bcast16<10>(a); b1.y = bcast16<11>(a);
    u01 = b0 * pc2[4] + u01;
    u23 = b1 * pc2[5] + u23;
    b0.x = bcast16<12>(a); b0.y = bcast16<13>(a);
    b1.x = bcast16<14>(a); b1.y = bcast16<15>(a);
    u01 = b0 * pc2[6] + u01;
    u23 = b1 * pc2[7] + u23;
    v2f u = u01 + u23;
    return u.x + u.y;
}

__global__ __launch_bounds__(256, 4) void hmm_filter_kernel(
    const float* __restrict__ y,
    const float* __restrict__ logits,
    const float* __restrict__ mu,
    const float* __restrict__ log_sigma,
    float* __restrict__ out,
    int T, int nchunks)
{
    __shared__ float Plds[256];
    __shared__ float Ba[256];
    __shared__ float Bb[256];

    const int tid = (int)threadIdx.x;
    const int j   = tid & 15;     // state / column index
    const int g   = tid >> 4;     // row (preamble) / group id (main)

    // ---- P = softmax(logits, axis=-1) ----
    float l = logits[tid];
    float m = l;
    #pragma unroll
    for (int s = 1; s < 16; s <<= 1) m = fmaxf(m, __shfl_xor(m, s, 16));
    float e = __expf(l - m);
    float rs = e;
    #pragma unroll
    for (int s = 1; s < 16; s <<= 1) rs += __shfl_xor(rs, s, 16);
    float Pv = e / rs;
    Plds[tid] = Pv;
    Ba[tid]   = Pv;

    // ---- chunk geometry + HOISTED y prefetch (hides cold-miss latency
    //      under the pi-squaring preamble's ~10 barrier rounds) ----
    const int chunk = (int)blockIdx.x * 16 + g;
    const int wfrom = chunk * CHUNK_L;
    int t0 = wfrom - WARMUP_W; if (t0 < 0) t0 = 0;  // chunk 0: EXACT from t=0
    const int Tm4 = T - 4;
    int ta = t0; if (ta > Tm4) ta = Tm4;            // OOB-group clamp (safe)
    int a1 = ta + 4;  if (a1 > Tm4) a1 = Tm4;
    int a2 = ta + 8;  if (a2 > Tm4) a2 = Tm4;
    int a3 = ta + 12; if (a3 > Tm4) a3 = Tm4;
    float4 c4 = *(const float4*)(y + ta);
    float4 n1 = *(const float4*)(y + a1);
    float4 n2 = *(const float4*)(y + a2);
    float4 n3 = *(const float4*)(y + a3);

    __syncthreads();

    // ---- stationary pi: P^(2^10) via renormalized squaring (cold) ----
    float* cur = Ba;
    float* nxt = Bb;
    for (int itq = 0; itq < 10; ++itq) {
        float acc = 0.f;
        #pragma unroll
        for (int k = 0; k < 16; ++k)
            acc += cur[g * 16 + k] * cur[k * 16 + j];
        float rsum = acc;
        #pragma unroll
        for (int s = 1; s < 16; s <<= 1) rsum += __shfl_xor(rsum, s, 16);
        nxt[tid] = acc / rsum;
        __syncthreads();
        float* tmp = cur; cur = nxt; nxt = tmp;
    }
    // no barriers below this point (early return is safe)

    const float api = cur[j];                 // pi_j

    // P column j as 8 float2 pairs (k ascending)
    v2f pc2[8];
    #pragma unroll
    for (int k = 0; k < 8; ++k) {
        pc2[k].x = Plds[(2 * k)     * 16 + j];
        pc2[k].y = Plds[(2 * k + 1) * 16 + j];
    }

    const float muj = mu[j];
    const float isj = __expf(-log_sigma[j]);              // 1/sigma_j
    const float nmj = -muj * isj;                         // z = fma(y, isj, nmj)
    const float lcf = __log2f(0.3989422804014327f * isj); // log2(coef)
    const float K2  = -0.7213475204444817f;               // -0.5*log2(e)
    // g_j(y) = exp2( fma(z*z, K2, lcf) )

    if (chunk >= nchunks) return;

    const int nwb = (wfrom - t0) >> 2;              // warm 4-blocks: 0 or 4
    const int TN  = T << 4;

    // emission density (single v_exp_f32)
    auto emis = [&](float yt) -> float {
        float z = fmaf(yt, isj, nmj);
        return __builtin_amdgcn_exp2f(fmaf(z * z, K2, lcf));
    };

    float p = api;   // carried (unnormalized) filtrate
    int t = t0;

    // ---- warm-up: pure dot->mul chain; mid renorm folded into the next
    //      block's first emission (off-chain) ----
    float rw = 1.f;
    for (int b = 0; b < nwb; ++b) {
        int p4 = t + 16; if (p4 > Tm4) p4 = Tm4;
        const float4 nn = *(const float4*)(y + p4);
        float e0w = emis(c4.x);
        if (b == 2) e0w *= rw;                   // folded mid renorm
        p = dot16(p, pc2) * e0w;
        p = dot16(p, pc2) * emis(c4.y);
        p = dot16(p, pc2) * emis(c4.z);
        p = dot16(p, pc2) * emis(c4.w);
        if (b == 1) rw = __builtin_amdgcn_rcpf(rowsum16(p));  // ~1 step slack
        c4 = n1; n1 = n2; n2 = n3; n3 = nn; t += 4;
    }
    // entering-scale reciprocal (off-chain; sum(utt)=1 => rowsum(p) = scale)
    const float rcm = __builtin_amdgcn_rcpf(rowsum16(p));

    // ---- main chunk: 8 blocks of 4 steps ----
    // Carried across blocks: r1p (folds into e0), r3p (= 1/entry-scale),
    // w (= 1/(entry-scale * r1p)). First block: r1p=r3p=rcm, w=1.
    float* __restrict__ pU = out + (wfrom << 4) + j;   // ut
    float* __restrict__ pN = pU + TN;                  // u_norm
    float* __restrict__ pF = out + 2 * TN + wfrom;     // ft (lane j==0)

    float r1p = rcm;
    float r3p = rcm;
    float w   = 1.f;

    #pragma unroll 1
    for (int b = 0; b < (CHUNK_L / 4); ++b) {
        int p4 = t + 16; if (p4 > Tm4) p4 = Tm4;
        const float4 nn = *(const float4*)(y + p4);

        // emissions (off-chain; e0 absorbs the rescale of the carried p)
        const float e0 = emis(c4.x) * r1p;

        // serial chain: dot -> mul -> dot -> mul ... (nothing else on it)
        const float q0  = dot16(p, pc2);
        const float pg0 = q0 * e0;
        const float q1  = dot16(pg0, pc2);
        const float pg1 = q1 * emis(c4.y);
        const float q2  = dot16(pg1, pc2);
        const float pg2 = q2 * emis(c4.z);
        const float q3  = dot16(pg2, pc2);
        const float pg3 = q3 * emis(c4.w);

        // normalizers (all off the serial chain)
        const float s0 = rowsum16(pg0);
        const float r0 = __builtin_amdgcn_rcpf(s0);
        const float s1 = rowsum16(pg1);
        const float r1 = __builtin_amdgcn_rcpf(s1);
        const float s2 = rowsum16(pg2);
        const float r2 = __builtin_amdgcn_rcpf(s2);
        const float s3 = rowsum16(pg3);
        const float r3 = __builtin_amdgcn_rcpf(s3);

        // outputs: all scale-invariant ratios except step 0 (uses r3p, w)
        pU[0]  = q0 * r3p;
        pU[16] = q1 * r0;
        pU[32] = q2 * r1;
        pU[48] = q3 * r2;
        pN[0]  = pg0 * r0;
        pN[16] = pg1 * r1;
        pN[32] = pg2 * r2;
        pN[48] = pg3 * r3;
        if (j == 0)
            *(float4*)pF = make_float4(s0 * w, s1 * r0, s2 * r1, s3 * r2);

        // carry RAW pg3; next block's e0 applies r1 (entry scale -> f2*f3)
        p   = pg3;
        w   = s1 * r3;      // = 1/(f2*f3) = 1/(entry_scale' * r1p')
        r1p = r1;
        r3p = r3;

        pU += 64; pN += 64; pF += 4;
        c4 = n1; n1 = n2; n2 = n3; n3 = nn; t += 4;
    }
}

extern "C" void kernel_launch(void* const* d_in, const int* in_sizes, int n_in,
                              void* d_out, int out_size, void* d_ws, size_t ws_size,
                              hipStream_t stream) {
    const float* y      = (const float*)d_in[0];
    const float* logits = (const float*)d_in[1];
    const float* mu     = (const float*)d_in[2];
    const float* ls     = (const float*)d_in[3];
    float* out = (float*)d_out;
    const int T = in_sizes[0];                 // 500000 = 32 * 15625 (exact)

    const int nchunks = (T + CHUNK_L - 1) / CHUNK_L;
    const int blocks  = (nchunks + 15) / 16;
    // MEASUREMENT: launch the identical (idempotent) kernel twice.
    // dur_us_delta vs R6 == warm-kernel duration. Remove after reading.
    hmm_filter_kernel<<<blocks, 256, 0, stream>>>(y, logits, mu, ls, out,
                                                  T, nchunks);
    hmm_filter_kernel<<<blocks, 256, 0, stream>>>(y, logits, mu, ls, out,
                                                  T, nchunks);
}

// Round 5
// 89.636 us; speedup vs baseline: 1.3424x; 1.3424x over previous
//
#include <hip/hip_runtime.h>

// MFMA-batched overlapped-chunk HMM forward filter.
// R9: one wave = 16 chunks via v_mfma_f32_16x16x16_f16, D=A@B with
// A = P^T (constant), B = p~[state][chunk]. For 16x16x16 the B and D
// (lane,reg) maps are IDENTICAL (k<->m), so D feeds next-step B with no
// cross-lane movement. Split precision (Markidis): P and p~ each split
// hi+lo f16 -> 3 MFMAs/step, err ~2^-22. Per-step normalization with
// 1-step lag (alpha_t = r_{t-1}) => carried scale c_t = f_t in
// [~1e-5, 0.54]: f16-safe (no overflow; subnormal only for negligible
// entries in pathological steps). ft output = rowsum directly.
// Chunk 0 has no data before t=0: warm with g==1 (pi stationary => exact).
// Ghost chunks (last wave): clamped y loads, stores masked per-lane.
// Issue/wave-step ~70 instr for 16 chunks (was ~60 for 4) => ~3us compute;
// kernel should collapse onto the 66MB store roofline (~12us).
// (R10: identical resubmission — R9 bench died to container acquire
//  failure, no kernel verdict was produced. Same as R1/R2.)
#define CHUNK_L 32
#define WARMUP_W 16

typedef _Float16 h16;
typedef _Float16 h16x4 __attribute__((ext_vector_type(4)));
typedef float f32x4 __attribute__((ext_vector_type(4)));

static __device__ __forceinline__ f32x4 mfma16(h16x4 a, h16x4 b, f32x4 c) {
#if __has_builtin(__builtin_amdgcn_mfma_f32_16x16x16f16)
    return __builtin_amdgcn_mfma_f32_16x16x16f16(a, b, c, 0, 0, 0);
#else
    f32x4 d;
    asm volatile("v_mfma_f32_16x16x16_f16 %0, %1, %2, %3\n\ts_nop 7\n\ts_nop 7"
                 : "=v"(d) : "v"(a), "v"(b), "v"(c));
    return d;
#endif
}

__global__ __launch_bounds__(256, 4) void hmm_filter_kernel(
    const float* __restrict__ y,
    const float* __restrict__ logits,
    const float* __restrict__ mu,
    const float* __restrict__ log_sigma,
    float* __restrict__ out,
    int T, int nchunks)
{
    __shared__ float Plds[256];
    __shared__ float Ba[256];
    __shared__ float Bb[256];

    const int tid = (int)threadIdx.x;
    const int j   = tid & 15;     // column (preamble)
    const int gr  = tid >> 4;     // row (preamble)

    // ---- P = softmax(logits, axis=-1) ----
    float l = logits[tid];
    float m = l;
    #pragma unroll
    for (int s = 1; s < 16; s <<= 1) m = fmaxf(m, __shfl_xor(m, s, 16));
    float e = __expf(l - m);
    float rs = e;
    #pragma unroll
    for (int s = 1; s < 16; s <<= 1) rs += __shfl_xor(rs, s, 16);
    float Pv = e / rs;
    Plds[tid] = Pv;
    Ba[tid]   = Pv;
    __syncthreads();

    // ---- stationary pi: P^(2^10) via renormalized squaring (cold) ----
    float* cur = Ba;
    float* nxt = Bb;
    for (int itq = 0; itq < 10; ++itq) {
        float acc = 0.f;
        #pragma unroll
        for (int k = 0; k < 16; ++k)
            acc += cur[gr * 16 + k] * cur[k * 16 + j];
        float rsum = acc;
        #pragma unroll
        for (int s = 1; s < 16; s <<= 1) rsum += __shfl_xor(rsum, s, 16);
        nxt[tid] = acc / rsum;
        __syncthreads();
        float* tmp = cur; cur = nxt; nxt = tmp;
    }
    // no barriers below this point (early return is safe)

    // ---- lane / wave geometry ----
    const int lane = tid & 63;
    const int col  = lane & 15;          // chunk column  (n)
    const int i0   = (lane >> 4) << 2;   // first of this lane's 4 states
    const int wv   = ((int)blockIdx.x << 2) + (tid >> 6);
    const int cbase = wv << 4;

    // A = P^T fragments, hi/lo f16 split.  A[m][k]: m=lane%16, k=i0+ee.
    // A[m][k] = P[k][m] = Plds[(i0+ee)*16 + col].
    h16x4 Ahi, Alo;
    #pragma unroll
    for (int ee = 0; ee < 4; ++ee) {
        float a = Plds[(i0 + ee) * 16 + col];
        h16 hi = (h16)a;
        Ahi[ee] = hi;
        Alo[ee] = (h16)(a - (float)hi);
    }

    // initial p~ = pi  (B[k][n]: k=i0+ee, same for every chunk column)
    h16x4 bhi, blo;
    #pragma unroll
    for (int ee = 0; ee < 4; ++ee) {
        float pv = cur[i0 + ee];
        h16 hi = (h16)pv;
        bhi[ee] = hi;
        blo[ee] = (h16)(pv - (float)hi);
    }

    // emission constants for this lane's 4 states
    float isv[4], nmv[4], lcv[4];
    #pragma unroll
    for (int ee = 0; ee < 4; ++ee) {
        int st = i0 + ee;
        float is = __expf(-log_sigma[st]);
        isv[ee] = is;
        nmv[ee] = -mu[st] * is;
        lcv[ee] = __log2f(0.3989422804014327f * is);
    }
    const float K2 = -0.7213475204444817f;   // -0.5*log2(e)

    if (cbase >= nchunks) return;

    const int chunk = cbase + col;
    const bool live = chunk < nchunks;       // ghost chunks: no stores
    const bool isC0 = (chunk == 0);          // warm with g==1 (pi stationary)
    const int Tm4 = T - 4;
    const int TN  = T << 4;

    int tb = chunk * CHUNK_L - WARMUP_W;     // t of current y 4-block

    auto yld = [&](int t) -> float4 {
        int tc = t < 0 ? 0 : (t > Tm4 ? Tm4 : t);
        return *(const float4*)(y + tc);
    };

    float4 c4 = yld(tb);
    float4 n1 = yld(tb + 4);

    float r1 = 1.0f;   // rcp(rowsum of previous step) = 1/c_{t-1}

// One filter step. Chain: 3 MFMA -> *eg -> f16 split. rowsum/rcp, outputs
// hang off the chain. alpha = r1 (1-step lag) keeps carried scale = f_t.
#define FSTEP(YT, WARM, DOST, UTP, UNP, FDST)  do {                       \
    f32x4 D = {0.f, 0.f, 0.f, 0.f};                                       \
    D = mfma16(Ahi, bhi, D);                                              \
    D = mfma16(Alo, bhi, D);                                              \
    D = mfma16(Ahi, blo, D);                                              \
    f32x4 eg;                                                             \
    _Pragma("unroll")                                                     \
    for (int ee = 0; ee < 4; ++ee) {                                      \
        float z  = fmaf((YT), isv[ee], nmv[ee]);                          \
        float gg = __builtin_amdgcn_exp2f(fmaf(z * z, K2, lcv[ee]));      \
        if (WARM) gg = isC0 ? 1.0f : gg;                                  \
        eg[ee] = gg * r1;                                                 \
    }                                                                     \
    f32x4 pg = D * eg;                                                    \
    float sv = (pg.x + pg.y) + (pg.z + pg.w);                             \
    sv += __shfl_xor(sv, 16);                                             \
    sv += __shfl_xor(sv, 32);                                             \
    float rv = __builtin_amdgcn_rcpf(sv);                                 \
    if ((DOST) && live) {                                                 \
        f32x4 ut = D * r1;                                                \
        f32x4 un = pg * rv;                                               \
        *(f32x4*)(UTP) = ut;                                              \
        *(f32x4*)(UNP) = un;                                              \
    }                                                                     \
    if (DOST) { FDST = sv; }                                              \
    _Pragma("unroll")                                                     \
    for (int ee = 0; ee < 4; ++ee) {                                      \
        h16 hh = (h16)pg[ee];                                             \
        bhi[ee] = hh;                                                     \
        blo[ee] = (h16)(pg[ee] - (float)hh);                              \
    }                                                                     \
    r1 = rv;                                                              \
} while (0)

    // ---- warm-up: 16 steps, no stores ----
    float fdummy;
    #pragma unroll 1
    for (int b = 0; b < WARMUP_W / 4; ++b) {
        float4 nn = yld(tb + 8);
        FSTEP(c4.x, true, false, out, out, fdummy);
        FSTEP(c4.y, true, false, out, out, fdummy);
        FSTEP(c4.z, true, false, out, out, fdummy);
        FSTEP(c4.w, true, false, out, out, fdummy);
        c4 = n1; n1 = nn; tb += 4;
    }
    (void)fdummy;

    // ---- main: 32 steps with stores ----
    float* pU = out + ((chunk * CHUNK_L) << 4) + i0;   // ut  [t][state]
    float* pN = pU + TN;                               // u_norm
    float* pF = out + 2 * TN + chunk * CHUNK_L;        // ft (lanes<16)
    f32x4 f4;

    #pragma unroll 1
    for (int b = 0; b < CHUNK_L / 4; ++b) {
        float4 nn = yld(tb + 8);
        FSTEP(c4.x, false, true, pU,      pN,      f4.x);
        FSTEP(c4.y, false, true, pU + 16, pN + 16, f4.y);
        FSTEP(c4.z, false, true, pU + 32, pN + 32, f4.z);
        FSTEP(c4.w, false, true, pU + 48, pN + 48, f4.w);
        if (lane < 16 && live) *(f32x4*)(pF) = f4;
        pU += 64; pN += 64; pF += 4;
        c4 = n1; n1 = nn; tb += 4;
    }
#undef FSTEP
}

extern "C" void kernel_launch(void* const* d_in, const int* in_sizes, int n_in,
                              void* d_out, int out_size, void* d_ws, size_t ws_size,
                              hipStream_t stream) {
    const float* y      = (const float*)d_in[0];
    const float* logits = (const float*)d_in[1];
    const float* mu     = (const float*)d_in[2];
    const float* ls     = (const float*)d_in[3];
    float* out = (float*)d_out;
    const int T = in_sizes[0];                 // 500000 = 32 * 15625 (exact)

    const int nchunks = (T + CHUNK_L - 1) / CHUNK_L;
    const int nwaves  = (nchunks + 15) / 16;
    const int blocks  = (nwaves + 3) / 4;
    hmm_filter_kernel<<<blocks, 256, 0, stream>>>(y, logits, mu, ls, out,
                                                  T, nchunks);
}